// Round 9
// baseline (784.998 us; speedup 1.0000x reference)
//
#include <hip/hip_runtime.h>

// GCNEncoder — round 9: R8-passing kernel + bf16 storage for h1/h2 (halves
// gather bytes/edge; accumulation & agg1/BN/GEMM2 stay fp32) + 16-way
// prefetch in the CSR gathers (same accumulation order -> order-identical).
// b1 cancels exactly through BatchNorm -> skipped.

__device__ __forceinline__ unsigned short f2bf(float f) {
    unsigned int u = __float_as_uint(f);
    unsigned int r = (u + 0x7FFFu + ((u >> 16) & 1u)) >> 16;   // RNE
    return (unsigned short)r;
}
__device__ __forceinline__ float bf2f(unsigned short h) {
    return __uint_as_float(((unsigned int)h) << 16);
}
__device__ __forceinline__ unsigned int pack2bf(float a, float b) {
    return (unsigned int)f2bf(a) | ((unsigned int)f2bf(b) << 16);
}
__device__ __forceinline__ void fma4(float4& acc, float s, const float4& w) {
    acc.x += s * w.x; acc.y += s * w.y; acc.z += s * w.z; acc.w += s * w.w;
}

// ---------- dtype probe: edge_index may be int64 or int32 ----------
__global__ void k_detect(const int* __restrict__ ei32, int* __restrict__ flag) {
    if (threadIdx.x == 0 && blockIdx.x == 0) {
        int o = 0;
        for (int q = 0; q < 16; ++q) o |= ei32[2 * q + 1];
        flag[0] = (o == 0) ? 1 : 0;  // 1 => int64 (high dwords all zero)
    }
}

// ---------- degree count (real edges at dst) ----------
__global__ __launch_bounds__(256) void k_count(const void* __restrict__ eiv,
                                               int* __restrict__ cnt,
                                               const int* __restrict__ flag,
                                               int E, int N) {
    int e = blockIdx.x * 256 + threadIdx.x;
    if (e >= E) return;
    int d;
    if (flag[0]) d = (int)((const long long*)eiv)[E + e];
    else         d = ((const int*)eiv)[E + e];
    if ((unsigned)d < (unsigned)N) atomicAdd(&cnt[d], 1);
}

// ---------- dis = rsqrt(deg+1); CSR region alloc via plain atomicAdd ----------
__global__ __launch_bounds__(256) void k_disalloc(const int* __restrict__ cnt,
                                                  float* __restrict__ dis,
                                                  int* __restrict__ rowptr,
                                                  int* __restrict__ rowcur,
                                                  int* __restrict__ total, int N) {
    int i = blockIdx.x * 256 + threadIdx.x;
    if (i >= N) return;
    int c = cnt[i];
    dis[i] = rsqrtf((float)c + 1.0f);
    int pos = atomicAdd(total, c);   // region order arbitrary; that's fine
    rowptr[i] = pos;
    rowcur[i] = pos;
}

// ---------- CSR fill ----------
__global__ __launch_bounds__(256) void k_fill(const void* __restrict__ eiv,
                                              int* __restrict__ rowcur,
                                              int* __restrict__ elist,
                                              const int* __restrict__ flag,
                                              int E, int N) {
    int e = blockIdx.x * 256 + threadIdx.x;
    if (e >= E) return;
    int s, d;
    if (flag[0]) {
        s = (int)((const long long*)eiv)[e];
        d = (int)((const long long*)eiv)[E + e];
    } else {
        s = ((const int*)eiv)[e];
        d = ((const int*)eiv)[E + e];
    }
    if ((unsigned)s >= (unsigned)N || (unsigned)d >= (unsigned)N) return;
    int p = atomicAdd(&rowcur[d], 1);
    elist[p] = s;
}

// ---------- weight transpose: dst[k][o] = src[o][k], K=128 ----------
__global__ __launch_bounds__(256) void k_transpose(const float* __restrict__ src,
                                                   float* __restrict__ dst, int O) {
    int idx = blockIdx.x * 256 + threadIdx.x;
    if (idx >= O * 128) return;
    int k = idx & 127, o = idx >> 7;
    dst[k * O + o] = src[o * 128 + k];
}

// ---------- GEMM1: h1b[n][o] (bf16) = x[n]·W1[o], W as WT1[k][o] ----------
__global__ __launch_bounds__(256) void k_gemm1(const float* __restrict__ x,
                                               const float* __restrict__ WT1,
                                               uint2* __restrict__ h1b, int N) {
    int t = threadIdx.x;
    int q = t & 31, g = t >> 5;
    int n0 = blockIdx.x * 32 + g * 4;
    const float4* xr0 = (const float4*)x + (size_t)min(n0 + 0, N - 1) * 32;
    const float4* xr1 = (const float4*)x + (size_t)min(n0 + 1, N - 1) * 32;
    const float4* xr2 = (const float4*)x + (size_t)min(n0 + 2, N - 1) * 32;
    const float4* xr3 = (const float4*)x + (size_t)min(n0 + 3, N - 1) * 32;
    const float4* wt = (const float4*)WT1;   // row k: 32 float4
    float4 acc0 = make_float4(0.f, 0.f, 0.f, 0.f), acc1 = acc0, acc2 = acc0, acc3 = acc0;
    for (int kq = 0; kq < 32; ++kq) {
        float4 a0 = xr0[kq], a1 = xr1[kq], a2 = xr2[kq], a3 = xr3[kq];
        float4 w0 = wt[(4 * kq + 0) * 32 + q];   // coalesced across q-lanes
        float4 w1 = wt[(4 * kq + 1) * 32 + q];
        float4 w2 = wt[(4 * kq + 2) * 32 + q];
        float4 w3 = wt[(4 * kq + 3) * 32 + q];
        fma4(acc0, a0.x, w0); fma4(acc0, a0.y, w1); fma4(acc0, a0.z, w2); fma4(acc0, a0.w, w3);
        fma4(acc1, a1.x, w0); fma4(acc1, a1.y, w1); fma4(acc1, a1.z, w2); fma4(acc1, a1.w, w3);
        fma4(acc2, a2.x, w0); fma4(acc2, a2.y, w1); fma4(acc2, a2.z, w2); fma4(acc2, a2.w, w3);
        fma4(acc3, a3.x, w0); fma4(acc3, a3.y, w1); fma4(acc3, a3.z, w2); fma4(acc3, a3.w, w3);
    }
    // pack to bf16x4 (uint2), row = 32 uint2
    if (n0 + 0 < N) h1b[(size_t)(n0 + 0) * 32 + q] = make_uint2(pack2bf(acc0.x, acc0.y), pack2bf(acc0.z, acc0.w));
    if (n0 + 1 < N) h1b[(size_t)(n0 + 1) * 32 + q] = make_uint2(pack2bf(acc1.x, acc1.y), pack2bf(acc1.z, acc1.w));
    if (n0 + 2 < N) h1b[(size_t)(n0 + 2) * 32 + q] = make_uint2(pack2bf(acc2.x, acc2.y), pack2bf(acc2.z, acc2.w));
    if (n0 + 3 < N) h1b[(size_t)(n0 + 3) * 32 + q] = make_uint2(pack2bf(acc3.x, acc3.y), pack2bf(acc3.z, acc3.w));
}

// ---------- layer-1 gather: bf16 rows, 16-way prefetch, fp32 accumulate ----------
__global__ __launch_bounds__(256) void k_agg1(const unsigned int* __restrict__ h1b,
                                              const float* __restrict__ dis,
                                              const int* __restrict__ rowptr,
                                              const int* __restrict__ cnt,
                                              const int* __restrict__ elist,
                                              float* __restrict__ agg1, int N) {
    int lane = threadIdx.x & 63;
    int i = blockIdx.x * 4 + (threadIdx.x >> 6);
    if (i >= N) return;
    float accx = 0.f, accy = 0.f;
    int base = rowptr[i], c = cnt[i];
    int j = 0;
    for (; j + 16 <= c; j += 16) {
        int ss[16];
#pragma unroll
        for (int r = 0; r < 16; ++r) ss[r] = elist[base + j + r];   // independent
        float ww[16];
#pragma unroll
        for (int r = 0; r < 16; ++r) ww[r] = dis[ss[r]];            // independent
        unsigned int vv[16];
#pragma unroll
        for (int r = 0; r < 16; ++r) vv[r] = h1b[(size_t)ss[r] * 64 + lane];  // 256B/row
#pragma unroll
        for (int r = 0; r < 16; ++r) {
            accx += ww[r] * bf2f((unsigned short)(vv[r] & 0xFFFF));
            accy += ww[r] * bf2f((unsigned short)(vv[r] >> 16));
        }
    }
    for (; j < c; ++j) {
        int s = elist[base + j];
        float w = dis[s];
        unsigned int v = h1b[(size_t)s * 64 + lane];
        accx += w * bf2f((unsigned short)(v & 0xFFFF));
        accy += w * bf2f((unsigned short)(v >> 16));
    }
    float di = dis[i];
    unsigned int sv = h1b[(size_t)i * 64 + lane];
    float2 r;
    r.x = di * accx + di * di * bf2f((unsigned short)(sv & 0xFFFF));
    r.y = di * accy + di * di * bf2f((unsigned short)(sv >> 16));
    ((float2*)agg1)[(size_t)i * 64 + lane] = r;
}

// ---------- BN stats (proven, fp32 agg1) ----------
__global__ __launch_bounds__(256) void k_bnstats(const float* __restrict__ agg1,
                                                 float* __restrict__ stats, int N) {
    int t = threadIdx.x;
    int f = t & 127, half = t >> 7;
    float s = 0.f, sq = 0.f;
    int stride = gridDim.x * 2;
    for (int r = blockIdx.x * 2 + half; r < N; r += stride) {
        float v = agg1[r * 128 + f];
        s += v; sq += v * v;
    }
    __shared__ float ls[256], lq[256];
    ls[t] = s; lq[t] = sq;
    __syncthreads();
    if (t < 128) {
        atomicAdd(&stats[f], ls[t] + ls[t + 128]);
        atomicAdd(&stats[128 + f], lq[t] + lq[t + 128]);
    }
}

// ---------- BN finalize (proven) ----------
__global__ void k_bnfin(float* __restrict__ stats, const float* __restrict__ gamma,
                        const float* __restrict__ beta, int N) {
    int f = threadIdx.x;
    if (f >= 128) return;
    float invN = 1.0f / (float)N;
    float mean = stats[f] * invN;
    float var = stats[128 + f] * invN - mean * mean;
    var = fmaxf(var, 0.f);
    float inv = rsqrtf(var + 1e-5f);
    float sc = gamma[f] * inv;
    stats[256 + f] = sc;
    stats[384 + f] = beta[f] - mean * sc;
}

// ---------- GEMM2: h2b[n][o] (bf16) = relu(bn(agg1[n]))·W2[o] ----------
__global__ __launch_bounds__(256) void k_gemm2(const float* __restrict__ agg1,
                                               const float* __restrict__ WT2,
                                               const float* __restrict__ stats,
                                               uint2* __restrict__ h2b, int N) {
    int t = threadIdx.x;
    int q = t & 15, g = t >> 4;
    int n0 = blockIdx.x * 64 + g * 4;
    const float4* ar0 = (const float4*)agg1 + (size_t)min(n0 + 0, N - 1) * 32;
    const float4* ar1 = (const float4*)agg1 + (size_t)min(n0 + 1, N - 1) * 32;
    const float4* ar2 = (const float4*)agg1 + (size_t)min(n0 + 2, N - 1) * 32;
    const float4* ar3 = (const float4*)agg1 + (size_t)min(n0 + 3, N - 1) * 32;
    const float4* wt = (const float4*)WT2;   // row k: 16 float4
    const float4* st = (const float4*)stats;
    float4 acc0 = make_float4(0.f, 0.f, 0.f, 0.f), acc1 = acc0, acc2 = acc0, acc3 = acc0;
    for (int kq = 0; kq < 32; ++kq) {
        float4 sc = st[64 + kq], sh = st[96 + kq];
        float4 a0 = ar0[kq], a1 = ar1[kq], a2 = ar2[kq], a3 = ar3[kq];
        float4 r0, r1, r2, r3;
        r0.x = fmaxf(a0.x * sc.x + sh.x, 0.f); r0.y = fmaxf(a0.y * sc.y + sh.y, 0.f);
        r0.z = fmaxf(a0.z * sc.z + sh.z, 0.f); r0.w = fmaxf(a0.w * sc.w + sh.w, 0.f);
        r1.x = fmaxf(a1.x * sc.x + sh.x, 0.f); r1.y = fmaxf(a1.y * sc.y + sh.y, 0.f);
        r1.z = fmaxf(a1.z * sc.z + sh.z, 0.f); r1.w = fmaxf(a1.w * sc.w + sh.w, 0.f);
        r2.x = fmaxf(a2.x * sc.x + sh.x, 0.f); r2.y = fmaxf(a2.y * sc.y + sh.y, 0.f);
        r2.z = fmaxf(a2.z * sc.z + sh.z, 0.f); r2.w = fmaxf(a2.w * sc.w + sh.w, 0.f);
        r3.x = fmaxf(a3.x * sc.x + sh.x, 0.f); r3.y = fmaxf(a3.y * sc.y + sh.y, 0.f);
        r3.z = fmaxf(a3.z * sc.z + sh.z, 0.f); r3.w = fmaxf(a3.w * sc.w + sh.w, 0.f);
        float4 w0 = wt[(4 * kq + 0) * 16 + q];   // coalesced across q-lanes
        float4 w1 = wt[(4 * kq + 1) * 16 + q];
        float4 w2 = wt[(4 * kq + 2) * 16 + q];
        float4 w3 = wt[(4 * kq + 3) * 16 + q];
        fma4(acc0, r0.x, w0); fma4(acc0, r0.y, w1); fma4(acc0, r0.z, w2); fma4(acc0, r0.w, w3);
        fma4(acc1, r1.x, w0); fma4(acc1, r1.y, w1); fma4(acc1, r1.z, w2); fma4(acc1, r1.w, w3);
        fma4(acc2, r2.x, w0); fma4(acc2, r2.y, w1); fma4(acc2, r2.z, w2); fma4(acc2, r2.w, w3);
        fma4(acc3, r3.x, w0); fma4(acc3, r3.y, w1); fma4(acc3, r3.z, w2); fma4(acc3, r3.w, w3);
    }
    // pack to bf16x4 (uint2), row = 16 uint2
    if (n0 + 0 < N) h2b[(size_t)(n0 + 0) * 16 + q] = make_uint2(pack2bf(acc0.x, acc0.y), pack2bf(acc0.z, acc0.w));
    if (n0 + 1 < N) h2b[(size_t)(n0 + 1) * 16 + q] = make_uint2(pack2bf(acc1.x, acc1.y), pack2bf(acc1.z, acc1.w));
    if (n0 + 2 < N) h2b[(size_t)(n0 + 2) * 16 + q] = make_uint2(pack2bf(acc2.x, acc2.y), pack2bf(acc2.z, acc2.w));
    if (n0 + 3 < N) h2b[(size_t)(n0 + 3) * 16 + q] = make_uint2(pack2bf(acc3.x, acc3.y), pack2bf(acc3.z, acc3.w));
}

// ---------- layer-2 gather: bf16 rows, 16-way prefetch, self-loop+b2 fused ----------
__global__ __launch_bounds__(256) void k_agg2(const unsigned short* __restrict__ h2b,
                                              const float* __restrict__ dis,
                                              const int* __restrict__ rowptr,
                                              const int* __restrict__ cnt,
                                              const int* __restrict__ elist,
                                              const float* __restrict__ b2,
                                              float* __restrict__ out, int N) {
    int lane = threadIdx.x & 63;
    int i = blockIdx.x * 4 + (threadIdx.x >> 6);
    if (i >= N) return;
    float acc = 0.f;
    int base = rowptr[i], c = cnt[i];
    int j = 0;
    for (; j + 16 <= c; j += 16) {
        int ss[16];
#pragma unroll
        for (int r = 0; r < 16; ++r) ss[r] = elist[base + j + r];   // independent
        float ww[16];
#pragma unroll
        for (int r = 0; r < 16; ++r) ww[r] = dis[ss[r]];            // independent
        unsigned short vv[16];
#pragma unroll
        for (int r = 0; r < 16; ++r) vv[r] = h2b[(size_t)ss[r] * 64 + lane];  // 128B/row
#pragma unroll
        for (int r = 0; r < 16; ++r) acc += ww[r] * bf2f(vv[r]);
    }
    for (; j < c; ++j) {
        int s = elist[base + j];
        float w = dis[s];
        acc += w * bf2f(h2b[(size_t)s * 64 + lane]);
    }
    float di = dis[i];
    float self = bf2f(h2b[(size_t)i * 64 + lane]);
    out[(size_t)i * 64 + lane] = di * acc + di * di * self + b2[lane];
}

extern "C" void kernel_launch(void* const* d_in, const int* in_sizes, int n_in,
                              void* d_out, int out_size, void* d_ws, size_t ws_size,
                              hipStream_t stream) {
    const float* x     = (const float*)d_in[0];
    const void*  ei    = d_in[1];            // int64 or int32, probed on device
    const float* W1    = (const float*)d_in[2];
    // d_in[3] = b1: cancels exactly through BatchNorm -> skipped
    const float* gamma = (const float*)d_in[4];
    const float* beta  = (const float*)d_in[5];
    const float* W2    = (const float*)d_in[6];
    const float* b2    = (const float*)d_in[7];
    float* out = (float*)d_out;

    int N = in_sizes[0] / 128;
    int E = in_sizes[1] / 2;
    int NF = N * 128;

    // ---- workspace layout (~85 MB, within proven budget) ----
    int*   cnt    = (int*)d_ws;                          // N
    int*   rowptr = cnt + N;                             // N
    int*   rowcur = rowptr + N;                          // N
    int*   total4 = rowcur + N;                          // 4: [0]=alloc, [1]=flag
    float* stats  = (float*)(total4 + 4);                // 512
    float* dis    = stats + 512;                         // N
    int*   elist  = (int*)(dis + N);                     // E
    unsigned int* h1b = (unsigned int*)(elist + E);      // N*64 uints (bf16x2), 16B-aligned
    float* agg1   = (float*)(h1b + (size_t)N * 64);      // N*128 f32
    float* WT1    = agg1 + (size_t)NF;                   // 128*128
    float* WT2    = WT1 + 128 * 128;                     // 128*64
    unsigned int* h2b = h1b;                             // overlay: h1 dead after agg1

    hipMemsetAsync(cnt, 0, (size_t)N * sizeof(int), stream);
    hipMemsetAsync(total4, 0, (4 + 512) * sizeof(int), stream);

    int* flag = total4 + 1;
    k_detect<<<1, 64, 0, stream>>>((const int*)ei, flag);

    int gE   = (E + 255) / 256;
    int gN   = (N + 255) / 256;
    int gG1  = (N + 31) / 32;
    int gG2  = (N + 63) / 64;
    int gAgg = (N + 3) / 4;

    k_transpose<<<64, 256, 0, stream>>>(W1, WT1, 128);   // 16384 elems
    k_transpose<<<32, 256, 0, stream>>>(W2, WT2, 64);    // 8192 elems
    k_count<<<gE, 256, 0, stream>>>(ei, cnt, flag, E, N);
    k_disalloc<<<gN, 256, 0, stream>>>(cnt, dis, rowptr, rowcur, total4, N);
    k_fill<<<gE, 256, 0, stream>>>(ei, rowcur, elist, flag, E, N);
    k_gemm1<<<gG1, 256, 0, stream>>>(x, WT1, (uint2*)h1b, N);
    k_agg1<<<gAgg, 256, 0, stream>>>(h1b, dis, rowptr, cnt, elist, agg1, N);
    k_bnstats<<<500, 256, 0, stream>>>(agg1, stats, N);
    k_bnfin<<<1, 128, 0, stream>>>(stats, gamma, beta, N);
    k_gemm2<<<gG2, 256, 0, stream>>>(agg1, WT2, stats, (uint2*)h2b, N);
    k_agg2<<<gAgg, 256, 0, stream>>>((const unsigned short*)h2b, dis, rowptr, cnt, elist, b2, out, N);
}

// Round 10
// 684.838 us; speedup vs baseline: 1.1463x; 1.1463x over previous
//
#include <hip/hip_runtime.h>

// GCNEncoder — round 10: bf16 h-storage kept, but gathers restructured for
// concurrency: 8-way prefetch (R8-proven occupancy) and dis[s] pre-folded
// into h rows at GEMM output time (h1s = dis*h1, h2s = dis*h2) so the gather
// has no dependent dis load. agg[i] = dis_i*(sum_edges hs[s] + hs[i]).
// b1 cancels exactly through BatchNorm -> skipped.

__device__ __forceinline__ unsigned short f2bf(float f) {
    unsigned int u = __float_as_uint(f);
    unsigned int r = (u + 0x7FFFu + ((u >> 16) & 1u)) >> 16;   // RNE
    return (unsigned short)r;
}
__device__ __forceinline__ float bf2f(unsigned short h) {
    return __uint_as_float(((unsigned int)h) << 16);
}
__device__ __forceinline__ unsigned int pack2bf(float a, float b) {
    return (unsigned int)f2bf(a) | ((unsigned int)f2bf(b) << 16);
}
__device__ __forceinline__ void fma4(float4& acc, float s, const float4& w) {
    acc.x += s * w.x; acc.y += s * w.y; acc.z += s * w.z; acc.w += s * w.w;
}

// ---------- dtype probe: edge_index may be int64 or int32 ----------
__global__ void k_detect(const int* __restrict__ ei32, int* __restrict__ flag) {
    if (threadIdx.x == 0 && blockIdx.x == 0) {
        int o = 0;
        for (int q = 0; q < 16; ++q) o |= ei32[2 * q + 1];
        flag[0] = (o == 0) ? 1 : 0;  // 1 => int64 (high dwords all zero)
    }
}

// ---------- degree count (real edges at dst) ----------
__global__ __launch_bounds__(256) void k_count(const void* __restrict__ eiv,
                                               int* __restrict__ cnt,
                                               const int* __restrict__ flag,
                                               int E, int N) {
    int e = blockIdx.x * 256 + threadIdx.x;
    if (e >= E) return;
    int d;
    if (flag[0]) d = (int)((const long long*)eiv)[E + e];
    else         d = ((const int*)eiv)[E + e];
    if ((unsigned)d < (unsigned)N) atomicAdd(&cnt[d], 1);
}

// ---------- dis = rsqrt(deg+1); CSR region alloc via plain atomicAdd ----------
__global__ __launch_bounds__(256) void k_disalloc(const int* __restrict__ cnt,
                                                  float* __restrict__ dis,
                                                  int* __restrict__ rowptr,
                                                  int* __restrict__ rowcur,
                                                  int* __restrict__ total, int N) {
    int i = blockIdx.x * 256 + threadIdx.x;
    if (i >= N) return;
    int c = cnt[i];
    dis[i] = rsqrtf((float)c + 1.0f);
    int pos = atomicAdd(total, c);   // region order arbitrary; that's fine
    rowptr[i] = pos;
    rowcur[i] = pos;
}

// ---------- CSR fill ----------
__global__ __launch_bounds__(256) void k_fill(const void* __restrict__ eiv,
                                              int* __restrict__ rowcur,
                                              int* __restrict__ elist,
                                              const int* __restrict__ flag,
                                              int E, int N) {
    int e = blockIdx.x * 256 + threadIdx.x;
    if (e >= E) return;
    int s, d;
    if (flag[0]) {
        s = (int)((const long long*)eiv)[e];
        d = (int)((const long long*)eiv)[E + e];
    } else {
        s = ((const int*)eiv)[e];
        d = ((const int*)eiv)[E + e];
    }
    if ((unsigned)s >= (unsigned)N || (unsigned)d >= (unsigned)N) return;
    int p = atomicAdd(&rowcur[d], 1);
    elist[p] = s;
}

// ---------- weight transpose: dst[k][o] = src[o][k], K=128 ----------
__global__ __launch_bounds__(256) void k_transpose(const float* __restrict__ src,
                                                   float* __restrict__ dst, int O) {
    int idx = blockIdx.x * 256 + threadIdx.x;
    if (idx >= O * 128) return;
    int k = idx & 127, o = idx >> 7;
    dst[k * O + o] = src[o * 128 + k];
}

// ---------- GEMM1: h1s[n][o] (bf16) = dis[n] * (x[n]·W1[o]) ----------
__global__ __launch_bounds__(256) void k_gemm1(const float* __restrict__ x,
                                               const float* __restrict__ WT1,
                                               const float* __restrict__ dis,
                                               uint2* __restrict__ h1b, int N) {
    int t = threadIdx.x;
    int q = t & 31, g = t >> 5;
    int n0 = blockIdx.x * 32 + g * 4;
    int m0 = min(n0 + 0, N - 1), m1 = min(n0 + 1, N - 1);
    int m2 = min(n0 + 2, N - 1), m3 = min(n0 + 3, N - 1);
    const float4* xr0 = (const float4*)x + (size_t)m0 * 32;
    const float4* xr1 = (const float4*)x + (size_t)m1 * 32;
    const float4* xr2 = (const float4*)x + (size_t)m2 * 32;
    const float4* xr3 = (const float4*)x + (size_t)m3 * 32;
    const float4* wt = (const float4*)WT1;   // row k: 32 float4
    float4 acc0 = make_float4(0.f, 0.f, 0.f, 0.f), acc1 = acc0, acc2 = acc0, acc3 = acc0;
    for (int kq = 0; kq < 32; ++kq) {
        float4 a0 = xr0[kq], a1 = xr1[kq], a2 = xr2[kq], a3 = xr3[kq];
        float4 w0 = wt[(4 * kq + 0) * 32 + q];   // coalesced across q-lanes
        float4 w1 = wt[(4 * kq + 1) * 32 + q];
        float4 w2 = wt[(4 * kq + 2) * 32 + q];
        float4 w3 = wt[(4 * kq + 3) * 32 + q];
        fma4(acc0, a0.x, w0); fma4(acc0, a0.y, w1); fma4(acc0, a0.z, w2); fma4(acc0, a0.w, w3);
        fma4(acc1, a1.x, w0); fma4(acc1, a1.y, w1); fma4(acc1, a1.z, w2); fma4(acc1, a1.w, w3);
        fma4(acc2, a2.x, w0); fma4(acc2, a2.y, w1); fma4(acc2, a2.z, w2); fma4(acc2, a2.w, w3);
        fma4(acc3, a3.x, w0); fma4(acc3, a3.y, w1); fma4(acc3, a3.z, w2); fma4(acc3, a3.w, w3);
    }
    float d0 = dis[m0], d1 = dis[m1], d2 = dis[m2], d3 = dis[m3];
    if (n0 + 0 < N) h1b[(size_t)(n0 + 0) * 32 + q] = make_uint2(pack2bf(d0 * acc0.x, d0 * acc0.y), pack2bf(d0 * acc0.z, d0 * acc0.w));
    if (n0 + 1 < N) h1b[(size_t)(n0 + 1) * 32 + q] = make_uint2(pack2bf(d1 * acc1.x, d1 * acc1.y), pack2bf(d1 * acc1.z, d1 * acc1.w));
    if (n0 + 2 < N) h1b[(size_t)(n0 + 2) * 32 + q] = make_uint2(pack2bf(d2 * acc2.x, d2 * acc2.y), pack2bf(d2 * acc2.z, d2 * acc2.w));
    if (n0 + 3 < N) h1b[(size_t)(n0 + 3) * 32 + q] = make_uint2(pack2bf(d3 * acc3.x, d3 * acc3.y), pack2bf(d3 * acc3.z, d3 * acc3.w));
}

// ---------- layer-1 gather: pre-scaled bf16 rows, 8-way prefetch ----------
// agg1[i] = dis_i * ( sum_edges h1s[s] + h1s[i] )
__global__ __launch_bounds__(256) void k_agg1(const unsigned int* __restrict__ h1b,
                                              const float* __restrict__ dis,
                                              const int* __restrict__ rowptr,
                                              const int* __restrict__ cnt,
                                              const int* __restrict__ elist,
                                              float* __restrict__ agg1, int N) {
    int lane = threadIdx.x & 63;
    int i = blockIdx.x * 4 + (threadIdx.x >> 6);
    if (i >= N) return;
    float accx = 0.f, accy = 0.f;
    int base = rowptr[i], c = cnt[i];
    int j = 0;
    for (; j + 8 <= c; j += 8) {
        int ss[8];
#pragma unroll
        for (int r = 0; r < 8; ++r) ss[r] = elist[base + j + r];   // independent
        unsigned int vv[8];
#pragma unroll
        for (int r = 0; r < 8; ++r) vv[r] = h1b[(size_t)ss[r] * 64 + lane];  // 256B/row
#pragma unroll
        for (int r = 0; r < 8; ++r) {
            accx += bf2f((unsigned short)(vv[r] & 0xFFFF));
            accy += bf2f((unsigned short)(vv[r] >> 16));
        }
    }
    for (; j < c; ++j) {
        int s = elist[base + j];
        unsigned int v = h1b[(size_t)s * 64 + lane];
        accx += bf2f((unsigned short)(v & 0xFFFF));
        accy += bf2f((unsigned short)(v >> 16));
    }
    float di = dis[i];
    unsigned int sv = h1b[(size_t)i * 64 + lane];
    float2 r;
    r.x = di * (accx + bf2f((unsigned short)(sv & 0xFFFF)));
    r.y = di * (accy + bf2f((unsigned short)(sv >> 16)));
    ((float2*)agg1)[(size_t)i * 64 + lane] = r;
}

// ---------- BN stats (proven, fp32 agg1) ----------
__global__ __launch_bounds__(256) void k_bnstats(const float* __restrict__ agg1,
                                                 float* __restrict__ stats, int N) {
    int t = threadIdx.x;
    int f = t & 127, half = t >> 7;
    float s = 0.f, sq = 0.f;
    int stride = gridDim.x * 2;
    for (int r = blockIdx.x * 2 + half; r < N; r += stride) {
        float v = agg1[r * 128 + f];
        s += v; sq += v * v;
    }
    __shared__ float ls[256], lq[256];
    ls[t] = s; lq[t] = sq;
    __syncthreads();
    if (t < 128) {
        atomicAdd(&stats[f], ls[t] + ls[t + 128]);
        atomicAdd(&stats[128 + f], lq[t] + lq[t + 128]);
    }
}

// ---------- BN finalize (proven) ----------
__global__ void k_bnfin(float* __restrict__ stats, const float* __restrict__ gamma,
                        const float* __restrict__ beta, int N) {
    int f = threadIdx.x;
    if (f >= 128) return;
    float invN = 1.0f / (float)N;
    float mean = stats[f] * invN;
    float var = stats[128 + f] * invN - mean * mean;
    var = fmaxf(var, 0.f);
    float inv = rsqrtf(var + 1e-5f);
    float sc = gamma[f] * inv;
    stats[256 + f] = sc;
    stats[384 + f] = beta[f] - mean * sc;
}

// ---------- GEMM2: h2s[n][o] (bf16) = dis[n] * (relu(bn(agg1[n]))·W2[o]) ----------
__global__ __launch_bounds__(256) void k_gemm2(const float* __restrict__ agg1,
                                               const float* __restrict__ WT2,
                                               const float* __restrict__ stats,
                                               const float* __restrict__ dis,
                                               uint2* __restrict__ h2b, int N) {
    int t = threadIdx.x;
    int q = t & 15, g = t >> 4;
    int n0 = blockIdx.x * 64 + g * 4;
    int m0 = min(n0 + 0, N - 1), m1 = min(n0 + 1, N - 1);
    int m2 = min(n0 + 2, N - 1), m3 = min(n0 + 3, N - 1);
    const float4* ar0 = (const float4*)agg1 + (size_t)m0 * 32;
    const float4* ar1 = (const float4*)agg1 + (size_t)m1 * 32;
    const float4* ar2 = (const float4*)agg1 + (size_t)m2 * 32;
    const float4* ar3 = (const float4*)agg1 + (size_t)m3 * 32;
    const float4* wt = (const float4*)WT2;   // row k: 16 float4
    const float4* st = (const float4*)stats;
    float4 acc0 = make_float4(0.f, 0.f, 0.f, 0.f), acc1 = acc0, acc2 = acc0, acc3 = acc0;
    for (int kq = 0; kq < 32; ++kq) {
        float4 sc = st[64 + kq], sh = st[96 + kq];
        float4 a0 = ar0[kq], a1 = ar1[kq], a2 = ar2[kq], a3 = ar3[kq];
        float4 r0, r1, r2, r3;
        r0.x = fmaxf(a0.x * sc.x + sh.x, 0.f); r0.y = fmaxf(a0.y * sc.y + sh.y, 0.f);
        r0.z = fmaxf(a0.z * sc.z + sh.z, 0.f); r0.w = fmaxf(a0.w * sc.w + sh.w, 0.f);
        r1.x = fmaxf(a1.x * sc.x + sh.x, 0.f); r1.y = fmaxf(a1.y * sc.y + sh.y, 0.f);
        r1.z = fmaxf(a1.z * sc.z + sh.z, 0.f); r1.w = fmaxf(a1.w * sc.w + sh.w, 0.f);
        r2.x = fmaxf(a2.x * sc.x + sh.x, 0.f); r2.y = fmaxf(a2.y * sc.y + sh.y, 0.f);
        r2.z = fmaxf(a2.z * sc.z + sh.z, 0.f); r2.w = fmaxf(a2.w * sc.w + sh.w, 0.f);
        r3.x = fmaxf(a3.x * sc.x + sh.x, 0.f); r3.y = fmaxf(a3.y * sc.y + sh.y, 0.f);
        r3.z = fmaxf(a3.z * sc.z + sh.z, 0.f); r3.w = fmaxf(a3.w * sc.w + sh.w, 0.f);
        float4 w0 = wt[(4 * kq + 0) * 16 + q];   // coalesced across q-lanes
        float4 w1 = wt[(4 * kq + 1) * 16 + q];
        float4 w2 = wt[(4 * kq + 2) * 16 + q];
        float4 w3 = wt[(4 * kq + 3) * 16 + q];
        fma4(acc0, r0.x, w0); fma4(acc0, r0.y, w1); fma4(acc0, r0.z, w2); fma4(acc0, r0.w, w3);
        fma4(acc1, r1.x, w0); fma4(acc1, r1.y, w1); fma4(acc1, r1.z, w2); fma4(acc1, r1.w, w3);
        fma4(acc2, r2.x, w0); fma4(acc2, r2.y, w1); fma4(acc2, r2.z, w2); fma4(acc2, r2.w, w3);
        fma4(acc3, r3.x, w0); fma4(acc3, r3.y, w1); fma4(acc3, r3.z, w2); fma4(acc3, r3.w, w3);
    }
    float d0 = dis[m0], d1 = dis[m1], d2 = dis[m2], d3 = dis[m3];
    if (n0 + 0 < N) h2b[(size_t)(n0 + 0) * 16 + q] = make_uint2(pack2bf(d0 * acc0.x, d0 * acc0.y), pack2bf(d0 * acc0.z, d0 * acc0.w));
    if (n0 + 1 < N) h2b[(size_t)(n0 + 1) * 16 + q] = make_uint2(pack2bf(d1 * acc1.x, d1 * acc1.y), pack2bf(d1 * acc1.z, d1 * acc1.w));
    if (n0 + 2 < N) h2b[(size_t)(n0 + 2) * 16 + q] = make_uint2(pack2bf(d2 * acc2.x, d2 * acc2.y), pack2bf(d2 * acc2.z, d2 * acc2.w));
    if (n0 + 3 < N) h2b[(size_t)(n0 + 3) * 16 + q] = make_uint2(pack2bf(d3 * acc3.x, d3 * acc3.y), pack2bf(d3 * acc3.z, d3 * acc3.w));
}

// ---------- layer-2 gather: pre-scaled bf16 rows, 8-way prefetch ----------
// out[i] = dis_i * ( sum_edges h2s[s] + h2s[i] ) + b2
__global__ __launch_bounds__(256) void k_agg2(const unsigned short* __restrict__ h2b,
                                              const float* __restrict__ dis,
                                              const int* __restrict__ rowptr,
                                              const int* __restrict__ cnt,
                                              const int* __restrict__ elist,
                                              const float* __restrict__ b2,
                                              float* __restrict__ out, int N) {
    int lane = threadIdx.x & 63;
    int i = blockIdx.x * 4 + (threadIdx.x >> 6);
    if (i >= N) return;
    float acc = 0.f;
    int base = rowptr[i], c = cnt[i];
    int j = 0;
    for (; j + 8 <= c; j += 8) {
        int ss[8];
#pragma unroll
        for (int r = 0; r < 8; ++r) ss[r] = elist[base + j + r];   // independent
        unsigned short vv[8];
#pragma unroll
        for (int r = 0; r < 8; ++r) vv[r] = h2b[(size_t)ss[r] * 64 + lane];  // 128B/row
#pragma unroll
        for (int r = 0; r < 8; ++r) acc += bf2f(vv[r]);
    }
    for (; j < c; ++j) {
        int s = elist[base + j];
        acc += bf2f(h2b[(size_t)s * 64 + lane]);
    }
    float di = dis[i];
    float self = bf2f(h2b[(size_t)i * 64 + lane]);
    out[(size_t)i * 64 + lane] = di * (acc + self) + b2[lane];
}

extern "C" void kernel_launch(void* const* d_in, const int* in_sizes, int n_in,
                              void* d_out, int out_size, void* d_ws, size_t ws_size,
                              hipStream_t stream) {
    const float* x     = (const float*)d_in[0];
    const void*  ei    = d_in[1];            // int64 or int32, probed on device
    const float* W1    = (const float*)d_in[2];
    // d_in[3] = b1: cancels exactly through BatchNorm -> skipped
    const float* gamma = (const float*)d_in[4];
    const float* beta  = (const float*)d_in[5];
    const float* W2    = (const float*)d_in[6];
    const float* b2    = (const float*)d_in[7];
    float* out = (float*)d_out;

    int N = in_sizes[0] / 128;
    int E = in_sizes[1] / 2;
    int NF = N * 128;

    // ---- workspace layout (~85 MB, within proven budget) ----
    int*   cnt    = (int*)d_ws;                          // N
    int*   rowptr = cnt + N;                             // N
    int*   rowcur = rowptr + N;                          // N
    int*   total4 = rowcur + N;                          // 4: [0]=alloc, [1]=flag
    float* stats  = (float*)(total4 + 4);                // 512
    float* dis    = stats + 512;                         // N
    int*   elist  = (int*)(dis + N);                     // E
    unsigned int* h1b = (unsigned int*)(elist + E);      // N*64 uints (bf16x2), 16B-aligned
    float* agg1   = (float*)(h1b + (size_t)N * 64);      // N*128 f32
    float* WT1    = agg1 + (size_t)NF;                   // 128*128
    float* WT2    = WT1 + 128 * 128;                     // 128*64
    unsigned int* h2b = h1b;                             // overlay: h1 dead after agg1

    hipMemsetAsync(cnt, 0, (size_t)N * sizeof(int), stream);
    hipMemsetAsync(total4, 0, (4 + 512) * sizeof(int), stream);

    int* flag = total4 + 1;
    k_detect<<<1, 64, 0, stream>>>((const int*)ei, flag);

    int gE   = (E + 255) / 256;
    int gN   = (N + 255) / 256;
    int gG1  = (N + 31) / 32;
    int gG2  = (N + 63) / 64;
    int gAgg = (N + 3) / 4;

    k_transpose<<<64, 256, 0, stream>>>(W1, WT1, 128);   // 16384 elems
    k_transpose<<<32, 256, 0, stream>>>(W2, WT2, 64);    // 8192 elems
    k_count<<<gE, 256, 0, stream>>>(ei, cnt, flag, E, N);
    k_disalloc<<<gN, 256, 0, stream>>>(cnt, dis, rowptr, rowcur, total4, N);
    k_fill<<<gE, 256, 0, stream>>>(ei, rowcur, elist, flag, E, N);
    k_gemm1<<<gG1, 256, 0, stream>>>(x, WT1, dis, (uint2*)h1b, N);
    k_agg1<<<gAgg, 256, 0, stream>>>(h1b, dis, rowptr, cnt, elist, agg1, N);
    k_bnstats<<<500, 256, 0, stream>>>(agg1, stats, N);
    k_bnfin<<<1, 128, 0, stream>>>(stats, gamma, beta, N);
    k_gemm2<<<gG2, 256, 0, stream>>>(agg1, WT2, stats, dis, (uint2*)h2b, N);
    k_agg2<<<gAgg, 256, 0, stream>>>((const unsigned short*)h2b, dis, rowptr, cnt, elist, b2, out, N);
}